// Round 3
// baseline (107.420 us; speedup 1.0000x reference)
//
#include <hip/hip_runtime.h>
#include <math.h>

#pragma clang fp contract(off)

#define N_ROIS     1500
#define NUM_CLS    81
#define FG         80
#define MAXC       1536      // per-class candidate capacity (worst case N_ROIS)
#define NMS_T      0.5f
#define SCORE_T    0.05f
#define MAX_DET    100
#define TOTAL      (FG * N_ROIS)
#define TPB        256
#define K1_BLOCKS  256
#define K2_TPB     1024
#define NCHUNK     ((N_ROIS + TPB - 1) / TPB)   // 6
#define SUBCAP     8192      // kth LDS subset capacity
#define SEG        N_ROIS    // kept-list segment stride

// float <-> order-preserving uint
__device__ __forceinline__ unsigned f2s(float f) {
    unsigned u = __float_as_uint(f);
    return (u & 0x80000000u) ? ~u : (u | 0x80000000u);
}
__device__ __forceinline__ float s2f(unsigned u) {
    return __uint_as_float((u & 0x80000000u) ? (u & 0x7FFFFFFFu) : ~u);
}

// exact op-for-op decode matching the reference (fp contract off file-wide).
// Deterministic: K1 (IoU input) and K2 (output patch) calls bit-match.
__device__ __forceinline__ float4 decode_box(
    float x1, float y1, float x2, float y2,
    float dx0, float dy0, float dw0, float dh0,
    float Hm1, float Wm1, float* area)
{
    float w  = x2 - x1 + 1.0f;
    float h  = y2 - y1 + 1.0f;
    float cx = x1 + 0.5f * w;
    float cy = y1 + 0.5f * h;
    float dx = dx0 / 10.0f, dy = dy0 / 10.0f;
    float dw = dw0 / 5.0f,  dh = dh0 / 5.0f;
    float pcx = cx + w * dx;
    float pcy = cy + h * dy;
    float pw  = w * expf(dw);
    float ph  = h * expf(dh);
    float a1 = pcx - 0.5f * pw;
    float a2 = pcy - 0.5f * ph;
    float a3 = pcx + 0.5f * pw - 1.0f;
    float a4 = pcy + 0.5f * ph - 1.0f;
    a1 = fminf(fmaxf(a1, 0.0f), Wm1);
    a2 = fminf(fmaxf(a2, 0.0f), Hm1);
    a3 = fminf(fmaxf(a3, 0.0f), Wm1);
    a4 = fminf(fmaxf(a4, 0.0f), Hm1);
    *area = (a3 - a1 + 1.0f) * (a4 - a2 + 1.0f);
    return make_float4(a1, a2, a3, a4);
}

// ---------------- K1 (256 blocks, plain launch, NO in-kernel device sync) --
// blocks 0..79:  per-class NMS. Kept entries go to a PER-CLASS segment of
//   packed uint64 keys [f2s(score):32 | roi_idx:16 | sorted_pos:16]
//   (position via LDS atomic — order within class irrelevant downstream)
//   and cnt[b] is stored unconditionally, so NO workspace pre-init
//   (memset dispatch) is needed: poison-safe.
//   WS usage: FG*SEG*8 + FG*4 = 960,320 B — 1/3 of the verified baseline's
//   2.88 MB, so workspace overflow is impossible by construction.
// blocks 80..255: fill out (dets=0, cls_idx=r/1500+1, keep=0), disjoint
//   from everything the NMS blocks write.
// Kernel boundary provides the single device-scope release (grid.sync()
// costs ~25 us on 8-XCD MI355X; kernel-boundary sync is free).
__global__ __launch_bounds__(TPB) void nms_k1(
    const float* __restrict__ rois,    // (N,5)
    const float* __restrict__ deltas,  // (N, 4*81)
    const float* __restrict__ prob,    // (N, 81)
    const float* __restrict__ iminfo,  // (1,3)
    unsigned long long* __restrict__ keptKey,  // FG*SEG, segmented
    int* __restrict__ cnt,             // FG per-class kept counts
    float* __restrict__ out)
{
    const int tid  = threadIdx.x;
    const int lane = tid & 63;
    const int wv   = tid >> 6;
    const int b    = blockIdx.x;

    if (b >= FG) {
        // ---- fill blocks: dets=0, cls_idx, keep=0 (float4, grid-stride) ----
        const float4 z4 = make_float4(0.f, 0.f, 0.f, 0.f);
        const int stride = (K1_BLOCKS - FG) * TPB;
        int g = (b - FG) * TPB + tid;

        float4* dets4 = (float4*)out;                       // 180000
        for (int i = g; i < TOTAL * 6 / 4; i += stride) dets4[i] = z4;

        float4* cls4  = (float4*)(out + (size_t)TOTAL * 6); // 30000
        float4* keep4 = (float4*)(out + (size_t)TOTAL * 7);
        for (int i = g; i < TOTAL / 4; i += stride) {
            float fc = (float)((i * 4) / N_ROIS + 1);       // 1500%4==0
            cls4[i]  = make_float4(fc, fc, fc, fc);
            keep4[i] = z4;
        }
        return;
    }

    __shared__ unsigned long long key[MAXC];   // keys; later the mask matrix
    __shared__ unsigned long long skey[MAXC];  // rank-sorted keys
    __shared__ float4 box4[MAXC];
    __shared__ float  areaA[MAXC];
    __shared__ unsigned char keepf[MAXC], supp[MAXC];
    __shared__ int mcnt, lcnt;

    const int c = b + 1;              // class 1..80

    if (tid == 0) { mcnt = 0; lcnt = 0; }
    __syncthreads();

    // --- compaction: batch-load prob column, then wave-ballot compact ---
    float sv[NCHUNK];
    #pragma unroll
    for (int t = 0; t < NCHUNK; ++t) {
        int i = t * TPB + tid;
        sv[t] = (i < N_ROIS) ? prob[i * NUM_CLS + c] : 0.0f;
    }
    #pragma unroll
    for (int t = 0; t < NCHUNK; ++t) {
        int i = t * TPB + tid;
        bool val = (i < N_ROIS) && (sv[t] > SCORE_T);
        unsigned long long m = __ballot(val);
        int base = 0;
        if (lane == 0 && m) base = atomicAdd(&mcnt, __popcll(m));
        base = __shfl(base, 0, 64);
        if (val) {
            int pos = base + __popcll(m & ((1ull << lane) - 1ull));
            key[pos] = ((unsigned long long)(~f2s(sv[t])) << 32) | (unsigned)i;
        }
    }
    __syncthreads();
    const int M = mcnt;
    if (M == 0) { if (tid == 0) cnt[b] = 0; return; }

    const float Hm1 = iminfo[0] - 1.0f;
    const float Wm1 = iminfo[1] - 1.0f;

    // --- phase A: prefetch raw roi/delta words for compact element `tid`
    //     (their latency hides under the O(M^2) rank loop below) ---
    const bool own = (tid < M);
    float x1 = 0.f, y1 = 0.f, x2 = 0.f, y2 = 0.f;
    float d0 = 0.f, d1 = 0.f, d2 = 0.f, d3 = 0.f;
    int myrank = 0;
    if (own) {
        unsigned long long kk = key[tid];
        int i = (int)(kk & 0xFFFFFFFFu);
        const float* rp = rois + i * 5;
        x1 = rp[1]; y1 = rp[2]; x2 = rp[3]; y2 = rp[4];
        const float* dp = deltas + i * (4 * NUM_CLS) + c * 4;
        d0 = dp[0]; d1 = dp[1]; d2 = dp[2]; d3 = dp[3];
    }

    // --- phase B: rank-by-counting sort (keys unique: score desc, idx asc
    //     => exact stable order); also clear flags; overflow items (M>TPB,
    //     never hit at this input scale) decode inline ---
    for (int ii = tid; ii < M; ii += TPB) {
        unsigned long long kk = key[ii];
        int cr = 0;
        #pragma unroll 4
        for (int j = 0; j < M; ++j) cr += (int)(key[j] < kk);
        skey[cr] = kk;
        keepf[ii] = 0; supp[ii] = 0;
        if (ii == tid) {
            myrank = cr;
        } else {
            // rare path (M > 256): decode here
            int i = (int)(kk & 0xFFFFFFFFu);
            const float* rp = rois + i * 5;
            const float* dp = deltas + i * (4 * NUM_CLS) + c * 4;
            float ar;
            float4 bx = decode_box(rp[1], rp[2], rp[3], rp[4],
                                   dp[0], dp[1], dp[2], dp[3], Hm1, Wm1, &ar);
            box4[cr] = bx; areaA[cr] = ar;
        }
    }
    // --- phase C: decode own element straight into its sorted slot ---
    if (own) {
        float ar;
        float4 bx = decode_box(x1, y1, x2, y2, d0, d1, d2, d3, Hm1, Wm1, &ar);
        box4[myrank] = bx; areaA[myrank] = ar;
    }
    __syncthreads();

    const int MW = (M + 63) >> 6;          // 64-bit words per mask row
    const bool fast = (M * MW <= MAXC);    // mask matrix fits in key[]

    if (fast) {
        // --- suppression bit-matrix: row r, bit j iff j>r && iou>0.5.
        //     Words w < r>>6 are identically zero: store 0, skip IoU. ---
        for (int r = wv; r < M; r += TPB / 64) {
            float4 br = box4[r];
            float  ar = areaA[r];
            const int w0 = r >> 6;
            if (lane == 0)
                for (int w = 0; w < w0; ++w) key[r * MW + w] = 0ull;
            for (int w = w0; w < MW; ++w) {
                int col = (w << 6) | lane;
                bool inb = (col < M);
                int j = inb ? col : 0;
                float4 bj = box4[j];
                float  aj = areaA[j];
                float iw = fminf(br.z, bj.z) - fmaxf(br.x, bj.x) + 1.0f;
                float ih = fminf(br.w, bj.w) - fmaxf(br.y, bj.y) + 1.0f;
                iw = fmaxf(iw, 0.0f);
                ih = fmaxf(ih, 0.0f);
                float inter = iw * ih;
                float iou = inter / ((ar + aj) - inter);
                bool pred = inb && (col > r) && (iou > NMS_T);
                unsigned long long mk = __ballot(pred);
                if (lane == 0) key[r * MW + w] = mk;
            }
        }
        __syncthreads();

        // --- serial scan, wave 0, prefetched register-only chain ---
        if (tid < 64) {
            const int lw = (tid < MW) ? tid : 0;
            unsigned long long acc = 0;        // suppressed bits, word `tid`
            unsigned long long mcur = key[lw]; // row 0
            for (int k = 0; k < M; ++k) {
                unsigned long long mnext =
                    (k + 1 < M) ? key[(k + 1) * MW + lw] : 0ull;
                int bit = (int)((acc >> (k & 63)) & 1ull);
                int sup = __shfl(bit, k >> 6, 64);
                if (!sup) {                    // wave-uniform branch
                    acc |= mcur;
                    if (tid == 0) keepf[k] = 1;
                }
                mcur = mnext;
            }
        }
        __syncthreads();
    } else {
        // --- fallback: iterative greedy NMS (correct for any M) ---
        for (int k = 0; k < M; ++k) {
            if (!supp[k]) {
                if (tid == 0) keepf[k] = 1;
                float4 bk = box4[k];
                float  ak = areaA[k];
                for (int j = k + 1 + tid; j < M; j += TPB) {
                    float4 bj = box4[j];
                    float  aj = areaA[j];
                    float iw = fminf(bk.z, bj.z) - fmaxf(bk.x, bj.x) + 1.0f;
                    float ih = fminf(bk.w, bj.w) - fmaxf(bk.y, bj.y) + 1.0f;
                    iw = fmaxf(iw, 0.0f);
                    ih = fmaxf(ih, 0.0f);
                    float inter = iw * ih;
                    float iou = inter / ((ak + aj) - inter);
                    if (iou > NMS_T) supp[j] = 1;
                }
            }
            __syncthreads();
        }
    }

    // --- push kept entries to this class's segment as packed keys ---
    const int seg = b * SEG;
    for (int k = tid; k < M; k += TPB) {
        if (keepf[k]) {
            int p = atomicAdd(&lcnt, 1);
            unsigned long long sk = skey[k];
            unsigned u = ~(unsigned)(sk >> 32);          // f2s(score)
            keptKey[seg + p] = ((unsigned long long)u << 32) |
                               ((sk & 0xFFFFull) << 16) |  // roi idx (<1500)
                               (unsigned long long)(unsigned)k; // sorted pos
        }
    }
    __syncthreads();
    if (tid == 0) cnt[b] = lcnt;
}

// digit pick over hist4: threads 0..255 own one bin each (waves 0..3).
// kk is snapshotted in stage 1 (before the mid barrier), so the single
// winner's s_kk/s_sp update in stage 2 cannot race the reads.
__device__ __forceinline__ void digit_pick(
    int (*h4)[256], int* wtot, unsigned* s_sp, int* s_kk,
    int tid, int lane, int wv)
{
    int h = 0, r = 0, kk = 0;
    if (tid < 256) {
        h = h4[0][tid] + h4[1][tid] + h4[2][tid] + h4[3][tid];
        r = h;
        #pragma unroll
        for (int off = 1; off < 64; off <<= 1) {
            int o = __shfl_down(r, off, 64);
            if (lane + off < 64) r += o;
        }
        if (lane == 0) wtot[wv] = r;
        kk = *s_kk;                       // safe snapshot (pre-barrier)
    }
    __syncthreads();
    if (tid < 256) {
        int hi = 0;
        #pragma unroll
        for (int w2 = 0; w2 < 4; ++w2) if (w2 > wv) hi += wtot[w2];
        const int S_ge = r + hi, S_gt = S_ge - h;
        if (S_gt < kk && S_ge >= kk) {    // exactly one thread
            *s_sp = (*s_sp << 8) | (unsigned)tid;
            *s_kk = kk - S_gt;
        }
    }
}

// ---------------- K2 (1 block x 1024 threads): kth select + patch ----------
// Reads the 80 per-class counts (no memset needed anywhere). Common case
// (n <= 8192): compact ALL f2s(score) words into LDS once (wave-per-segment,
// balanced), then 4 exact radix-256 rounds fully in LDS. Fallback
// (n > 8192): 4 rounds re-reading global segments. Then the SAME block
// patches rows with u >= u_kth (order-preserving compare == float compare),
// RE-DECODING each patched box (bit-identical to K1's decode).
__global__ __launch_bounds__(K2_TPB) void kth_patch_k2(
    const int* __restrict__ cnt,
    const unsigned long long* __restrict__ keptKey,
    const float* __restrict__ rois,
    const float* __restrict__ deltas,
    const float* __restrict__ iminfo,
    float* __restrict__ out)
{
    __shared__ int scnt[FG];
    __shared__ int hist4[4][256];     // 4 privatized copies (wave & 3)
    __shared__ unsigned sub[SUBCAP];  // 32 KB
    __shared__ int wtot[4];
    __shared__ int s_n, s_pos, s_kk;
    __shared__ unsigned s_sp;

    const int tid  = threadIdx.x;
    const int lane = tid & 63;
    const int wv   = tid >> 6;        // 0..15
    const int hp   = wv & 3;          // histogram copy

    if (tid < FG) scnt[tid] = cnt[tid];
    if (tid == 0) { s_pos = 0; s_sp = 0u; s_kk = MAX_DET; }
    __syncthreads();
    if (tid == 0) {
        int t = 0;
        for (int s = 0; s < FG; ++s) t += scnt[s];
        s_n = t;
    }
    __syncthreads();
    const int n = s_n;

    if (n > MAX_DET) {
        const bool inLds = (n <= SUBCAP);
        if (inLds) {
            // --- one global pass: compact all f2s words into sub[] ---
            for (int s = wv; s < FG; s += K2_TPB / 64) {
                const int c = scnt[s];
                const unsigned long long* kp = keptKey + s * SEG;
                for (int i0 = 0; i0 < c; i0 += 64) {
                    int i = i0 + lane;
                    bool ok = (i < c);
                    unsigned u = ok ? (unsigned)(kp[i] >> 32) : 0u;
                    int cc = c - i0; if (cc > 64) cc = 64;
                    int basep = 0;
                    if (lane == 0) basep = atomicAdd(&s_pos, cc);
                    basep = __shfl(basep, 0, 64);
                    if (ok) sub[basep + lane] = u;   // active lanes are a prefix
                }
            }
            __syncthreads();
            // --- 4 exact radix-256 rounds, all in LDS ---
            for (int d = 0; d < 4; ++d) {
                const int shift = 24 - 8 * d;
                if (tid < 256) {
                    hist4[0][tid] = 0; hist4[1][tid] = 0;
                    hist4[2][tid] = 0; hist4[3][tid] = 0;
                }
                __syncthreads();
                const unsigned pre = s_sp;
                for (int i = tid; i < n; i += K2_TPB) {
                    unsigned v = sub[i];
                    if (d == 0 || (v >> (shift + 8)) == pre)
                        atomicAdd(&hist4[hp][(v >> shift) & 255u], 1);
                }
                __syncthreads();
                digit_pick(hist4, wtot, &s_sp, &s_kk, tid, lane, wv);
                __syncthreads();
            }
        } else {
            // --- fallback: 4 rounds over global segments ---
            for (int d = 0; d < 4; ++d) {
                const int shift = 24 - 8 * d;
                if (tid < 256) {
                    hist4[0][tid] = 0; hist4[1][tid] = 0;
                    hist4[2][tid] = 0; hist4[3][tid] = 0;
                }
                __syncthreads();
                const unsigned pre = s_sp;
                for (int s = wv; s < FG; s += K2_TPB / 64) {
                    const int c = scnt[s];
                    const unsigned long long* kp = keptKey + s * SEG;
                    for (int i = lane; i < c; i += 64) {
                        unsigned v = (unsigned)(kp[i] >> 32);
                        if (d == 0 || (v >> (shift + 8)) == pre)
                            atomicAdd(&hist4[hp][(v >> shift) & 255u], 1);
                    }
                }
                __syncthreads();
                digit_pick(hist4, wtot, &s_sp, &s_kk, tid, lane, wv);
                __syncthreads();
            }
        }
    }
    __syncthreads();
    // u_kth: exact f2s of the 100th-largest kept score, or 0 (keep all —
    // scores are positive so every u has the sign-flip bit set, u > 0).
    const unsigned ukth = (n > MAX_DET) ? s_sp : 0u;

    const float Hm1 = iminfo[0] - 1.0f;
    const float Wm1 = iminfo[1] - 1.0f;

    // --- patch rows with u >= ukth: re-decode box, scattered stores ---
    for (int s = wv; s < FG; s += K2_TPB / 64) {
        const int c = scnt[s];
        const unsigned long long* kp = keptKey + s * SEG;
        for (int idx = lane; idx < c; idx += 64) {
            unsigned long long key = kp[idx];
            unsigned u = (unsigned)(key >> 32);
            if (u >= ukth) {
                int i = (int)((key >> 16) & 0xFFFFu);   // roi index
                int k = (int)(key & 0xFFFFu);           // sorted pos in class
                int r = s * N_ROIS + k;                 // output row
                const float* rp = rois + i * 5;
                const float* dp = deltas + i * (4 * NUM_CLS) + (s + 1) * 4;
                float ar;
                float4 b4 = decode_box(rp[1], rp[2], rp[3], rp[4],
                                       dp[0], dp[1], dp[2], dp[3],
                                       Hm1, Wm1, &ar);
                float* dst = out + (size_t)r * 6;
                dst[1] = b4.x; dst[2] = b4.y; dst[3] = b4.z;
                dst[4] = b4.w; dst[5] = s2f(u);
                out[(size_t)TOTAL * 7 + r] = 1.0f;
            }
        }
    }
}

extern "C" void kernel_launch(void* const* d_in, const int* in_sizes, int n_in,
                              void* d_out, int out_size, void* d_ws, size_t ws_size,
                              hipStream_t stream) {
    const float* rois   = (const float*)d_in[0];  // (1500,5)
    const float* deltas = (const float*)d_in[1];  // (1500,324)
    const float* prob   = (const float*)d_in[2];  // (1500,81)
    const float* iminfo = (const float*)d_in[3];  // (1,3)
    float* out = (float*)d_out;

    // workspace: FG*SEG packed uint64 keys + FG counts = 960,320 B total —
    // strictly less than the verified baseline's 2.88 MB usage, so overflow
    // is impossible. Everything read downstream is written unconditionally
    // this iteration -> no memset, poison-safe.
    unsigned long long* keptKey = (unsigned long long*)d_ws;  // FG*SEG
    int* cnt = (int*)(keptKey + FG * SEG);                    // FG

    nms_k1<<<K1_BLOCKS, TPB, 0, stream>>>(rois, deltas, prob, iminfo,
                                          keptKey, cnt, out);
    kth_patch_k2<<<1, K2_TPB, 0, stream>>>(cnt, keptKey, rois, deltas,
                                           iminfo, out);
}

// Round 4
// 104.347 us; speedup vs baseline: 1.0294x; 1.0294x over previous
//
#include <hip/hip_runtime.h>
#include <math.h>

#pragma clang fp contract(off)

#define N_ROIS     1500
#define NUM_CLS    81
#define FG         80
#define MAXC       1536      // per-class candidate capacity (worst case N_ROIS)
#define NMS_T      0.5f
#define SCORE_T    0.05f
#define MAX_DET    100
#define TOTAL      (FG * N_ROIS)
#define TPB        256
#define K1_BLOCKS  256
#define K2_TPB     1024
#define NCHUNK     ((N_ROIS + TPB - 1) / TPB)   // 6
#define SUBCAP     8192      // kth LDS subset capacity
#define SEG        N_ROIS    // kept-list segment stride

// float <-> order-preserving uint
__device__ __forceinline__ unsigned f2s(float f) {
    unsigned u = __float_as_uint(f);
    return (u & 0x80000000u) ? ~u : (u | 0x80000000u);
}
__device__ __forceinline__ float s2f(unsigned u) {
    return __uint_as_float((u & 0x80000000u) ? (u & 0x7FFFFFFFu) : ~u);
}

// exact op-for-op decode matching the reference (fp contract off file-wide)
__device__ __forceinline__ float4 decode_box(
    float x1, float y1, float x2, float y2,
    float dx0, float dy0, float dw0, float dh0,
    float Hm1, float Wm1, float* area)
{
    float w  = x2 - x1 + 1.0f;
    float h  = y2 - y1 + 1.0f;
    float cx = x1 + 0.5f * w;
    float cy = y1 + 0.5f * h;
    float dx = dx0 / 10.0f, dy = dy0 / 10.0f;
    float dw = dw0 / 5.0f,  dh = dh0 / 5.0f;
    float pcx = cx + w * dx;
    float pcy = cy + h * dy;
    float pw  = w * expf(dw);
    float ph  = h * expf(dh);
    float a1 = pcx - 0.5f * pw;
    float a2 = pcy - 0.5f * ph;
    float a3 = pcx + 0.5f * pw - 1.0f;
    float a4 = pcy + 0.5f * ph - 1.0f;
    a1 = fminf(fmaxf(a1, 0.0f), Wm1);
    a2 = fminf(fmaxf(a2, 0.0f), Hm1);
    a3 = fminf(fmaxf(a3, 0.0f), Wm1);
    a4 = fminf(fmaxf(a4, 0.0f), Hm1);
    *area = (a3 - a1 + 1.0f) * (a4 - a2 + 1.0f);
    return make_float4(a1, a2, a3, a4);
}

// ---------------- K1 (256 blocks, plain launch, NO in-kernel device sync) --
// blocks 0..79:  per-class NMS. Kept entries go to a PER-CLASS segment:
//   float4 box + packed uint64 key [f2s(score):32 | roi_idx:16 | pos:16]
//   (position via LDS atomic — order within class irrelevant downstream)
//   and cnt[b] is stored unconditionally -> NO workspace pre-init
//   (memset dispatch) needed: poison-safe. WS usage 2.88 MB << 256 MiB.
// blocks 80..255: fill out (dets=0, cls_idx=r/1500+1, keep=0), disjoint
//   from everything the NMS blocks write.
// Kernel boundary provides the single device-scope release (grid.sync()
// costs ~25 us on 8-XCD MI355X; kernel-boundary sync is free).
__global__ __launch_bounds__(TPB) void nms_k1(
    const float* __restrict__ rois,    // (N,5)
    const float* __restrict__ deltas,  // (N, 4*81)
    const float* __restrict__ prob,    // (N, 81)
    const float* __restrict__ iminfo,  // (1,3)
    float4* __restrict__ keptBox,      // FG*SEG, segmented
    unsigned long long* __restrict__ keptKey,  // FG*SEG, segmented
    int* __restrict__ cnt,             // FG per-class kept counts
    float* __restrict__ out)
{
    const int tid  = threadIdx.x;
    const int lane = tid & 63;
    const int wv   = tid >> 6;
    const int b    = blockIdx.x;

    if (b >= FG) {
        // ---- fill blocks: dets=0, cls_idx, keep=0 (float4, grid-stride) ----
        const float4 z4 = make_float4(0.f, 0.f, 0.f, 0.f);
        const int stride = (K1_BLOCKS - FG) * TPB;
        int g = (b - FG) * TPB + tid;

        float4* dets4 = (float4*)out;                       // 180000
        for (int i = g; i < TOTAL * 6 / 4; i += stride) dets4[i] = z4;

        float4* cls4  = (float4*)(out + (size_t)TOTAL * 6); // 30000
        float4* keep4 = (float4*)(out + (size_t)TOTAL * 7);
        for (int i = g; i < TOTAL / 4; i += stride) {
            float fc = (float)((i * 4) / N_ROIS + 1);       // 1500%4==0
            cls4[i]  = make_float4(fc, fc, fc, fc);
            keep4[i] = z4;
        }
        return;
    }

    __shared__ unsigned long long key[MAXC];   // keys; later the mask matrix
    __shared__ unsigned long long skey[MAXC];  // rank-sorted keys
    __shared__ float4 box4[MAXC];
    __shared__ float  areaA[MAXC];
    __shared__ unsigned char keepf[MAXC], supp[MAXC];
    __shared__ int mcnt, lcnt;

    const int c = b + 1;              // class 1..80

    if (tid == 0) { mcnt = 0; lcnt = 0; }
    __syncthreads();

    // --- compaction: batch-load prob column, then wave-ballot compact ---
    float sv[NCHUNK];
    #pragma unroll
    for (int t = 0; t < NCHUNK; ++t) {
        int i = t * TPB + tid;
        sv[t] = (i < N_ROIS) ? prob[i * NUM_CLS + c] : 0.0f;
    }
    #pragma unroll
    for (int t = 0; t < NCHUNK; ++t) {
        int i = t * TPB + tid;
        bool val = (i < N_ROIS) && (sv[t] > SCORE_T);
        unsigned long long m = __ballot(val);
        int base = 0;
        if (lane == 0 && m) base = atomicAdd(&mcnt, __popcll(m));
        base = __shfl(base, 0, 64);
        if (val) {
            int pos = base + __popcll(m & ((1ull << lane) - 1ull));
            key[pos] = ((unsigned long long)(~f2s(sv[t])) << 32) | (unsigned)i;
        }
    }
    __syncthreads();
    const int M = mcnt;
    if (M == 0) { if (tid == 0) cnt[b] = 0; return; }

    const float Hm1 = iminfo[0] - 1.0f;
    const float Wm1 = iminfo[1] - 1.0f;

    // --- phase A: prefetch raw roi/delta words for compact element `tid`
    //     (their latency hides under the O(M^2) rank loop below) ---
    const bool own = (tid < M);
    float x1 = 0.f, y1 = 0.f, x2 = 0.f, y2 = 0.f;
    float d0 = 0.f, d1 = 0.f, d2 = 0.f, d3 = 0.f;
    int myrank = 0;
    if (own) {
        unsigned long long kk = key[tid];
        int i = (int)(kk & 0xFFFFFFFFu);
        const float* rp = rois + i * 5;
        x1 = rp[1]; y1 = rp[2]; x2 = rp[3]; y2 = rp[4];
        const float* dp = deltas + i * (4 * NUM_CLS) + c * 4;
        d0 = dp[0]; d1 = dp[1]; d2 = dp[2]; d3 = dp[3];
    }

    // --- phase B: rank-by-counting sort (keys unique: score desc, idx asc
    //     => exact stable order); also clear flags; overflow items (M>TPB,
    //     never hit at this input scale) decode inline ---
    for (int ii = tid; ii < M; ii += TPB) {
        unsigned long long kk = key[ii];
        int cr = 0;
        #pragma unroll 4
        for (int j = 0; j < M; ++j) cr += (int)(key[j] < kk);
        skey[cr] = kk;
        keepf[ii] = 0; supp[ii] = 0;
        if (ii == tid) {
            myrank = cr;
        } else {
            // rare path (M > 256): decode here
            int i = (int)(kk & 0xFFFFFFFFu);
            const float* rp = rois + i * 5;
            const float* dp = deltas + i * (4 * NUM_CLS) + c * 4;
            float ar;
            float4 bx = decode_box(rp[1], rp[2], rp[3], rp[4],
                                   dp[0], dp[1], dp[2], dp[3], Hm1, Wm1, &ar);
            box4[cr] = bx; areaA[cr] = ar;
        }
    }
    // --- phase C: decode own element straight into its sorted slot ---
    if (own) {
        float ar;
        float4 bx = decode_box(x1, y1, x2, y2, d0, d1, d2, d3, Hm1, Wm1, &ar);
        box4[myrank] = bx; areaA[myrank] = ar;
    }
    __syncthreads();

    const int MW = (M + 63) >> 6;          // 64-bit words per mask row
    const bool fast = (M * MW <= MAXC);    // mask matrix fits in key[]

    if (fast) {
        // --- suppression bit-matrix: row r, bit j iff j>r && iou>0.5.
        //     Words w < r>>6 are identically zero: store 0, skip IoU. ---
        for (int r = wv; r < M; r += TPB / 64) {
            float4 br = box4[r];
            float  ar = areaA[r];
            const int w0 = r >> 6;
            if (lane == 0)
                for (int w = 0; w < w0; ++w) key[r * MW + w] = 0ull;
            for (int w = w0; w < MW; ++w) {
                int col = (w << 6) | lane;
                bool inb = (col < M);
                int j = inb ? col : 0;
                float4 bj = box4[j];
                float  aj = areaA[j];
                float iw = fminf(br.z, bj.z) - fmaxf(br.x, bj.x) + 1.0f;
                float ih = fminf(br.w, bj.w) - fmaxf(br.y, bj.y) + 1.0f;
                iw = fmaxf(iw, 0.0f);
                ih = fmaxf(ih, 0.0f);
                float inter = iw * ih;
                float iou = inter / ((ar + aj) - inter);
                bool pred = inb && (col > r) && (iou > NMS_T);
                unsigned long long mk = __ballot(pred);
                if (lane == 0) key[r * MW + w] = mk;
            }
        }
        __syncthreads();

        // --- serial scan, wave 0, prefetched register-only chain ---
        if (tid < 64) {
            const int lw = (tid < MW) ? tid : 0;
            unsigned long long acc = 0;        // suppressed bits, word `tid`
            unsigned long long mcur = key[lw]; // row 0
            for (int k = 0; k < M; ++k) {
                unsigned long long mnext =
                    (k + 1 < M) ? key[(k + 1) * MW + lw] : 0ull;
                int bit = (int)((acc >> (k & 63)) & 1ull);
                int sup = __shfl(bit, k >> 6, 64);
                if (!sup) {                    // wave-uniform branch
                    acc |= mcur;
                    if (tid == 0) keepf[k] = 1;
                }
                mcur = mnext;
            }
        }
        __syncthreads();
    } else {
        // --- fallback: iterative greedy NMS (correct for any M) ---
        for (int k = 0; k < M; ++k) {
            if (!supp[k]) {
                if (tid == 0) keepf[k] = 1;
                float4 bk = box4[k];
                float  ak = areaA[k];
                for (int j = k + 1 + tid; j < M; j += TPB) {
                    float4 bj = box4[j];
                    float  aj = areaA[j];
                    float iw = fminf(bk.z, bj.z) - fmaxf(bk.x, bj.x) + 1.0f;
                    float ih = fminf(bk.w, bj.w) - fmaxf(bk.y, bj.y) + 1.0f;
                    iw = fmaxf(iw, 0.0f);
                    ih = fmaxf(ih, 0.0f);
                    float inter = iw * ih;
                    float iou = inter / ((ak + aj) - inter);
                    if (iou > NMS_T) supp[j] = 1;
                }
            }
            __syncthreads();
        }
    }

    // --- push kept entries (box + packed key) to this class's segment ---
    const int seg = b * SEG;
    for (int k = tid; k < M; k += TPB) {
        if (keepf[k]) {
            int p = atomicAdd(&lcnt, 1);
            unsigned long long sk = skey[k];
            unsigned u = ~(unsigned)(sk >> 32);          // f2s(score)
            keptBox[seg + p] = box4[k];
            keptKey[seg + p] = ((unsigned long long)u << 32) |
                               ((sk & 0xFFFFull) << 16) |   // roi idx (<1500)
                               (unsigned long long)(unsigned)k; // sorted pos
        }
    }
    __syncthreads();
    if (tid == 0) cnt[b] = lcnt;
}

// digit pick over hist4: threads 0..255 own one bin each (waves 0..3).
// kk is snapshotted in stage 1 (before the mid barrier), so the single
// winner's s_kk/s_sp update in stage 2 cannot race the reads.
__device__ __forceinline__ void digit_pick(
    int (*h4)[256], int* wtot, unsigned* s_sp, int* s_kk,
    int tid, int lane, int wv)
{
    int h = 0, r = 0, kk = 0;
    if (tid < 256) {
        h = h4[0][tid] + h4[1][tid] + h4[2][tid] + h4[3][tid];
        r = h;
        #pragma unroll
        for (int off = 1; off < 64; off <<= 1) {
            int o = __shfl_down(r, off, 64);
            if (lane + off < 64) r += o;
        }
        if (lane == 0) wtot[wv] = r;
        kk = *s_kk;                       // safe snapshot (pre-barrier)
    }
    __syncthreads();
    if (tid < 256) {
        int hi = 0;
        #pragma unroll
        for (int w2 = 0; w2 < 4; ++w2) if (w2 > wv) hi += wtot[w2];
        const int S_ge = r + hi, S_gt = S_ge - h;
        if (S_gt < kk && S_ge >= kk) {    // exactly one thread
            *s_sp = (*s_sp << 8) | (unsigned)tid;
            *s_kk = kk - S_gt;
        }
    }
}

// ---------------- K2 (1 block x 1024 threads): kth select + patch ----------
// Reads the 80 per-class counts (no memset needed anywhere). Common case
// (n <= 8192): compact ALL f2s(score) words into LDS once (wave-per-segment,
// balanced), then 4 exact radix-256 rounds fully in LDS. Fallback
// (n > 8192): 4 rounds re-reading global segments. Then the SAME block
// patches rows with u >= u_kth (order-preserving unsigned compare == float
// compare, ties included) using the STORED box — no re-decode chain.
__global__ __launch_bounds__(K2_TPB) void kth_patch_k2(
    const int* __restrict__ cnt,
    const float4* __restrict__ keptBox,
    const unsigned long long* __restrict__ keptKey,
    float* __restrict__ out)
{
    __shared__ int scnt[FG];
    __shared__ int hist4[4][256];     // 4 privatized copies (wave & 3)
    __shared__ unsigned sub[SUBCAP];  // 32 KB
    __shared__ int wtot[4];
    __shared__ int s_n, s_pos, s_kk;
    __shared__ unsigned s_sp;

    const int tid  = threadIdx.x;
    const int lane = tid & 63;
    const int wv   = tid >> 6;        // 0..15
    const int hp   = wv & 3;          // histogram copy

    if (tid < FG) scnt[tid] = cnt[tid];
    if (tid == 0) { s_pos = 0; s_sp = 0u; s_kk = MAX_DET; }
    __syncthreads();
    // wave-parallel total (wave 0): lane t takes scnt[t] (+ scnt[64+t])
    if (tid < 64) {
        int v = scnt[tid] + ((tid < FG - 64) ? scnt[64 + tid] : 0);
        #pragma unroll
        for (int off = 32; off > 0; off >>= 1) v += __shfl_down(v, off, 64);
        if (tid == 0) s_n = v;
    }
    __syncthreads();
    const int n = s_n;

    if (n > MAX_DET) {
        const bool inLds = (n <= SUBCAP);
        if (inLds) {
            // --- one global pass: compact all f2s words into sub[] ---
            for (int s = wv; s < FG; s += K2_TPB / 64) {
                const int c = scnt[s];
                const unsigned long long* kp = keptKey + s * SEG;
                for (int i0 = 0; i0 < c; i0 += 64) {
                    int i = i0 + lane;
                    bool ok = (i < c);
                    unsigned u = ok ? (unsigned)(kp[i] >> 32) : 0u;
                    int cc = c - i0; if (cc > 64) cc = 64;
                    int basep = 0;
                    if (lane == 0) basep = atomicAdd(&s_pos, cc);
                    basep = __shfl(basep, 0, 64);
                    if (ok) sub[basep + lane] = u;   // active lanes are a prefix
                }
            }
            __syncthreads();
            // --- 4 exact radix-256 rounds, all in LDS ---
            for (int d = 0; d < 4; ++d) {
                const int shift = 24 - 8 * d;
                if (tid < 256) {
                    hist4[0][tid] = 0; hist4[1][tid] = 0;
                    hist4[2][tid] = 0; hist4[3][tid] = 0;
                }
                __syncthreads();
                const unsigned pre = s_sp;
                for (int i = tid; i < n; i += K2_TPB) {
                    unsigned v = sub[i];
                    if (d == 0 || (v >> (shift + 8)) == pre)
                        atomicAdd(&hist4[hp][(v >> shift) & 255u], 1);
                }
                __syncthreads();
                digit_pick(hist4, wtot, &s_sp, &s_kk, tid, lane, wv);
                __syncthreads();
            }
        } else {
            // --- fallback: 4 rounds over global segments ---
            for (int d = 0; d < 4; ++d) {
                const int shift = 24 - 8 * d;
                if (tid < 256) {
                    hist4[0][tid] = 0; hist4[1][tid] = 0;
                    hist4[2][tid] = 0; hist4[3][tid] = 0;
                }
                __syncthreads();
                const unsigned pre = s_sp;
                for (int s = wv; s < FG; s += K2_TPB / 64) {
                    const int c = scnt[s];
                    const unsigned long long* kp = keptKey + s * SEG;
                    for (int i = lane; i < c; i += 64) {
                        unsigned v = (unsigned)(kp[i] >> 32);
                        if (d == 0 || (v >> (shift + 8)) == pre)
                            atomicAdd(&hist4[hp][(v >> shift) & 255u], 1);
                    }
                }
                __syncthreads();
                digit_pick(hist4, wtot, &s_sp, &s_kk, tid, lane, wv);
                __syncthreads();
            }
        }
    }
    __syncthreads();
    // u_kth: exact f2s of the 100th-largest kept score, or 0 (keep all —
    // scores are positive so every u has the sign-flip bit set, u > 0).
    const unsigned ukth = (n > MAX_DET) ? s_sp : 0u;

    // --- patch rows with u >= ukth: stored box, scattered stores ---
    for (int s = wv; s < FG; s += K2_TPB / 64) {
        const int c = scnt[s];
        const int base = s * SEG;
        for (int idx = lane; idx < c; idx += 64) {
            unsigned long long key = keptKey[base + idx];
            unsigned u = (unsigned)(key >> 32);
            if (u >= ukth) {
                int k = (int)(key & 0xFFFFu);           // sorted pos in class
                int r = s * N_ROIS + k;                 // output row
                float4 b4 = keptBox[base + idx];
                float* dst = out + (size_t)r * 6;
                dst[1] = b4.x; dst[2] = b4.y; dst[3] = b4.z;
                dst[4] = b4.w; dst[5] = s2f(u);
                out[(size_t)TOTAL * 7 + r] = 1.0f;
            }
        }
    }
}

extern "C" void kernel_launch(void* const* d_in, const int* in_sizes, int n_in,
                              void* d_out, int out_size, void* d_ws, size_t ws_size,
                              hipStream_t stream) {
    const float* rois   = (const float*)d_in[0];  // (1500,5)
    const float* deltas = (const float*)d_in[1];  // (1500,324)
    const float* prob   = (const float*)d_in[2];  // (1500,81)
    const float* iminfo = (const float*)d_in[3];  // (1,3)
    float* out = (float*)d_out;

    // workspace: float4 first for 16B alignment. 2.88 MB total (<< 256 MiB
    // ws). Everything read downstream is written unconditionally this
    // iteration -> no memset, poison-safe.
    float4* keptBox = (float4*)d_ws;                           // FG*SEG
    unsigned long long* keptKey = (unsigned long long*)(keptBox + FG * SEG);
    int* cnt = (int*)(keptKey + FG * SEG);                     // FG

    nms_k1<<<K1_BLOCKS, TPB, 0, stream>>>(rois, deltas, prob, iminfo,
                                          keptBox, keptKey, cnt, out);
    kth_patch_k2<<<1, K2_TPB, 0, stream>>>(cnt, keptBox, keptKey, out);
}